// Round 24
// baseline (98.527 us; speedup 1.0000x reference)
//
#include <hip/hip_runtime.h>
#include <hip/hip_bf16.h>

// ---------------------------------------------------------------------------
// TRTAttention round 24: r23 (97.3) with NSPLIT 3->2 ONLY. Critical-path
// model (validated by the 3/4/6 sweep): worst-CU = blocks*prologue +
// iters*iter. NSPLIT=2 -> 432 blocks, worst CU 2 blocks = 2*pro + 36*iter
// (one prologue fewer than NSPLIT=3's 3*pro + 36*iter); o_part -33%.
// All else frozen: fused split_rope+relbias, merged prep, EXT2=128 attn +
// setprio, (256,3), fp16 lane-major NT o_part, 64x128 QKV, 32x64 proj.
// ---------------------------------------------------------------------------

typedef short bf16x8 __attribute__((ext_vector_type(8)));
typedef float f32x4  __attribute__((ext_vector_type(4)));
typedef _Float16 f16x4 __attribute__((ext_vector_type(4)));

namespace {
constexpr int LTOK = 2304;
constexpr int DIMC = 768;
constexpr int NH   = 12;
constexpr int HD   = 64;
constexpr int WG   = 48;
constexpr int QKVN = 2304;
constexpr int EXT2 = 128;             // 64 K | 2 oh_h | 48 oh_w | 14 zero
constexpr int NSPLIT = 2;
constexpr int KPS  = LTOK / NSPLIT;   // 1152
constexpr int NT   = KPS / 64;        // 18
constexpr int NQB2 = LTOK / 128;      // 18
constexpr float SCALE = 0.125f;
// merged prep kernel block ranges
constexpr int NB_ROPE = (LTOK * 32) / 256;          // 288
constexpr int NB_CAST = (LTOK * DIMC / 8) / 256;    // 864
constexpr int NB_TQKV = (QKVN / 32) * (DIMC / 32);  // 1728
constexpr int NB_TPRJ = (DIMC / 32) * (DIMC / 32);  // 576
}

__device__ __forceinline__ short f2b(float f) {
    __hip_bfloat16 h = __float2bfloat16(f);
    return *reinterpret_cast<short*>(&h);
}
__device__ __forceinline__ float b2f(short s) {
    return __uint_as_float(((unsigned)(unsigned short)s) << 16);
}
__device__ __forceinline__ void load16_to_lds(const short* g, short* l) {
    __builtin_amdgcn_global_load_lds(
        (__attribute__((address_space(1))) void*)g,
        (__attribute__((address_space(3))) void*)l,
        16, 0, 0);
}
__device__ __forceinline__ f16x4 nt_load_h4(const _Float16* p) {
    return __builtin_nontemporal_load((const f16x4*)p);
}

// ---------------- merged prep: rope tables | cast | 2 transposes -----------
__global__ __launch_bounds__(256) void prep_kernel(
    const float* __restrict__ x, const float* __restrict__ w_qkv,
    const float* __restrict__ w_proj,
    float* __restrict__ cost, float* __restrict__ sint,
    short* __restrict__ xb, short* __restrict__ wqkvT, short* __restrict__ wprojT)
{
    __shared__ float ts[32][36];
    const int b = blockIdx.x;
    const int t = threadIdx.x;
    if (b < NB_ROPE) {
        int idx = b * 256 + t;
        int j = idx & 31;
        int l = idx >> 5;
        float tt = (j < 16) ? (float)(l % WG) : (float)(l / WG);
        int fi = j & 15;
        float freq = powf(10000.0f, -(float)fi / 16.0f);
        float ang = tt * freq;
        cost[idx] = cosf(ang);
        sint[idx] = sinf(ang);
    } else if (b < NB_ROPE + NB_CAST) {
        int i = (b - NB_ROPE) * 256 + t;
        float4 a = ((const float4*)x)[2 * i];
        float4 bb = ((const float4*)x)[2 * i + 1];
        bf16x8 o;
        o[0] = f2b(a.x); o[1] = f2b(a.y); o[2] = f2b(a.z); o[3] = f2b(a.w);
        o[4] = f2b(bb.x); o[5] = f2b(bb.y); o[6] = f2b(bb.z); o[7] = f2b(bb.w);
        ((bf16x8*)xb)[i] = o;
    } else {
        const float* in;
        short* out;
        int R, C, c0, r0;
        if (b < NB_ROPE + NB_CAST + NB_TQKV) {
            int flat = b - NB_ROPE - NB_CAST;
            in = w_qkv; out = wqkvT; R = DIMC; C = QKVN;
            c0 = (flat % (QKVN / 32)) * 32;
            r0 = (flat / (QKVN / 32)) * 32;
        } else {
            int flat = b - NB_ROPE - NB_CAST - NB_TQKV;
            in = w_proj; out = wprojT; R = DIMC; C = DIMC;
            c0 = (flat % (DIMC / 32)) * 32;
            r0 = (flat / (DIMC / 32)) * 32;
        }
        {
            int r = t >> 3, cb = (t & 7) * 4;
            float4 v = *(const float4*)&in[(size_t)(r0 + r) * C + c0 + cb];
            ts[r][cb] = v.x; ts[r][cb + 1] = v.y; ts[r][cb + 2] = v.z; ts[r][cb + 3] = v.w;
        }
        __syncthreads();
        {
            int oc = t >> 3, rb = (t & 7) * 4;
            short4 s;
            s.x = f2b(ts[rb][oc]);     s.y = f2b(ts[rb + 1][oc]);
            s.z = f2b(ts[rb + 2][oc]); s.w = f2b(ts[rb + 3][oc]);
            *(short4*)&out[(size_t)(c0 + oc) * R + r0 + rb] = s;
        }
    }
}

// ------- bf16 MFMA GEMM 64x128 tile + bias, 256 thr / 4 waves (QKV) --------
__global__ __launch_bounds__(256) void gemm_bf16_64x128_kernel(
    const short* __restrict__ A, const short* __restrict__ Bt,
    const float* __restrict__ bias, float* __restrict__ C,
    int M, int N, int K)
{
    __shared__ short As[64 * 64];
    __shared__ short Bs[128 * 64];
    const int tid = threadIdx.x;
    const int bm = blockIdx.y * 64, bn = blockIdx.x * 128;
    const int w = tid >> 6, l = tid & 63;
    const int lm = l & 15, lk = (l >> 4) * 8;

    f32x4 acc[4][2];
    const f32x4 zf = {0.f, 0.f, 0.f, 0.f};
    #pragma unroll
    for (int m = 0; m < 4; ++m)
        #pragma unroll
        for (int n = 0; n < 2; ++n) acc[m][n] = zf;

    for (int k0 = 0; k0 < K; k0 += 64) {
        __syncthreads();
        #pragma unroll
        for (int p = 0; p < 2; ++p) {      // As: 512 loads
            int f = tid + p * 256;
            int row = f >> 3, c8 = (f & 7) * 8;
            load16_to_lds(&A[(size_t)(bm + row) * K + k0 + c8], &As[f * 8]);
        }
        #pragma unroll
        for (int p = 0; p < 4; ++p) {      // Bs: 1024 loads
            int f = tid + p * 256;
            int row = f >> 3, c8 = (f & 7) * 8;
            load16_to_lds(&Bt[(size_t)(bn + row) * K + k0 + c8], &Bs[f * 8]);
        }
        __syncthreads();
        #pragma unroll
        for (int kh = 0; kh < 2; ++kh) {
            bf16x8 a[4], b[2];
            #pragma unroll
            for (int m = 0; m < 4; ++m)
                a[m] = *(const bf16x8*)&As[(m * 16 + lm) * 64 + kh * 32 + lk];
            #pragma unroll
            for (int n = 0; n < 2; ++n)
                b[n] = *(const bf16x8*)&Bs[(w * 32 + n * 16 + lm) * 64 + kh * 32 + lk];
            #pragma unroll
            for (int m = 0; m < 4; ++m)
                #pragma unroll
                for (int n = 0; n < 2; ++n)
                    acc[m][n] = __builtin_amdgcn_mfma_f32_16x16x32_bf16(a[m], b[n], acc[m][n], 0, 0, 0);
        }
    }
    const int orow = (l >> 4) * 4;
    #pragma unroll
    for (int m = 0; m < 4; ++m) {
        #pragma unroll
        for (int n = 0; n < 2; ++n) {
            int col = bn + w * 32 + n * 16 + lm;
            float bv = bias[col];
            #pragma unroll
            for (int r = 0; r < 4; ++r) {
                int row = bm + m * 16 + orow + r;
                C[(size_t)row * N + col] = acc[m][n][r] + bv;
            }
        }
    }
}

// ------- bf16 MFMA GEMM 32x64 tile + bias, 256 thr / 4 waves (proj) --------
__global__ __launch_bounds__(256) void gemm32x64_kernel(
    const short* __restrict__ A, const short* __restrict__ Bt,
    const float* __restrict__ bias, float* __restrict__ C,
    int M, int N, int K)
{
    __shared__ short As[32 * 64];
    __shared__ short Bs[64 * 64];
    const int tid = threadIdx.x;
    const int bm = blockIdx.y * 32, bn = blockIdx.x * 64;
    const int w = tid >> 6, l = tid & 63;
    const int lm = l & 15, lk = (l >> 4) * 8;

    f32x4 acc[2];
    const f32x4 zf = {0.f, 0.f, 0.f, 0.f};
    acc[0] = zf; acc[1] = zf;

    for (int k0 = 0; k0 < K; k0 += 64) {
        __syncthreads();
        {
            int row = tid >> 3, c8 = (tid & 7) * 8;   // As: 256 loads
            load16_to_lds(&A[(size_t)(bm + row) * K + k0 + c8], &As[tid * 8]);
        }
        #pragma unroll
        for (int p = 0; p < 2; ++p) {                 // Bs: 512 loads
            int f = tid + p * 256;
            int row = f >> 3, c8 = (f & 7) * 8;
            load16_to_lds(&Bt[(size_t)(bn + row) * K + k0 + c8], &Bs[f * 8]);
        }
        __syncthreads();
        #pragma unroll
        for (int kh = 0; kh < 2; ++kh) {
            bf16x8 a[2], b;
            #pragma unroll
            for (int m = 0; m < 2; ++m)
                a[m] = *(const bf16x8*)&As[(m * 16 + lm) * 64 + kh * 32 + lk];
            b = *(const bf16x8*)&Bs[(w * 16 + lm) * 64 + kh * 32 + lk];
            #pragma unroll
            for (int m = 0; m < 2; ++m)
                acc[m] = __builtin_amdgcn_mfma_f32_16x16x32_bf16(a[m], b, acc[m], 0, 0, 0);
        }
    }
    const int orow = (l >> 4) * 4;
    #pragma unroll
    for (int m = 0; m < 2; ++m) {
        int col = bn + w * 16 + lm;
        float bv = bias[col];
        #pragma unroll
        for (int r = 0; r < 4; ++r) {
            int row = bm + m * 16 + orow + r;
            C[(size_t)row * N + col] = acc[m][r] + bv;
        }
    }
}

// ------ FUSED split qkv + rope + relbias -> q_ext (full), kb, vT, relh_g ---
__global__ __launch_bounds__(256) void split_rope_relbias_kernel(
    const float* __restrict__ qkv_raw,
    const float* __restrict__ cost, const float* __restrict__ sint,
    const float* __restrict__ rel_pos_h, const float* __restrict__ rel_pos_w,
    short* __restrict__ q_ext, short* __restrict__ kb, short* __restrict__ vT,
    short* __restrict__ relh_g)
{
    __shared__ short vt_s[64][72];
    __shared__ float qf32[64][68];
    __shared__ float rph_st[49][68];
    __shared__ float rpw_st[95][68];
    __shared__ short outw[64][64];
    __shared__ short outh[64][48];

    const int h = blockIdx.y;
    const int l0 = blockIdx.x * 64;
    const int hmin = l0 / WG;
    const int t = threadIdx.x;
    const int tok = t >> 2, dq = (t & 3) * 16;
    const int l = l0 + tok;
    const float* row = qkv_raw + (size_t)l * QKVN + h * HD;

    bf16x8 qe[2], kv[2];
    #pragma unroll
    for (int i = 0; i < 16; i += 4) {
        int d = dq + i;
        float4 tq = *(const float4*)&row[d];
        float4 tk = *(const float4*)&row[DIMC + d];
        float4 tv = *(const float4*)&row[2 * DIMC + d];
        float2 c01 = *(const float2*)&cost[l * 32 + d / 2];
        float2 s01 = *(const float2*)&sint[l * 32 + d / 2];
        float q0 = tq.x * c01.x - tq.y * s01.x;
        float q1 = tq.x * s01.x + tq.y * c01.x;
        float q2 = tq.z * c01.y - tq.w * s01.y;
        float q3 = tq.z * s01.y + tq.w * c01.y;
        qe[i >> 3][(i & 7) + 0] = f2b(q0 * SCALE);
        qe[i >> 3][(i & 7) + 1] = f2b(q1 * SCALE);
        qe[i >> 3][(i & 7) + 2] = f2b(q2 * SCALE);
        qe[i >> 3][(i & 7) + 3] = f2b(q3 * SCALE);
        kv[i >> 3][(i & 7) + 0] = f2b(tk.x * c01.x - tk.y * s01.x);
        kv[i >> 3][(i & 7) + 1] = f2b(tk.x * s01.x + tk.y * c01.x);
        kv[i >> 3][(i & 7) + 2] = f2b(tk.z * c01.y - tk.w * s01.y);
        kv[i >> 3][(i & 7) + 3] = f2b(tk.z * s01.y + tk.w * c01.y);
        vt_s[d + 0][tok] = f2b(tv.x);
        vt_s[d + 1][tok] = f2b(tv.y);
        vt_s[d + 2][tok] = f2b(tv.z);
        vt_s[d + 3][tok] = f2b(tv.w);
    }
    size_t kbase = ((size_t)h * LTOK + l) * HD + dq;
    *(bf16x8*)&kb[kbase]     = kv[0];
    *(bf16x8*)&kb[kbase + 8] = kv[1];
    size_t ebase = ((size_t)h * LTOK + l) * EXT2 + dq;
    *(bf16x8*)&q_ext[ebase]     = qe[0];
    *(bf16x8*)&q_ext[ebase + 8] = qe[1];
    #pragma unroll
    for (int i = 0; i < 8; ++i) {
        qf32[tok][dq + i]     = b2f(qe[0][i]);
        qf32[tok][dq + 8 + i] = b2f(qe[1][i]);
    }
    {
        const bf16x8 z8 = {0, 0, 0, 0, 0, 0, 0, 0};
        ((bf16x8*)outw)[t] = z8;
        ((bf16x8*)outw)[t + 256] = z8;
    }
    __syncthreads();
    {
        const int drow = t >> 2, lq = (t & 3) * 16;
        bf16x8 v0 = *(bf16x8*)&vt_s[drow][lq];
        bf16x8 v1 = *(bf16x8*)&vt_s[drow][lq + 8];
        size_t vbase = ((size_t)h * HD + drow) * LTOK + l0 + lq;
        *(bf16x8*)&vT[vbase]     = v0;
        *(bf16x8*)&vT[vbase + 8] = v1;
    }
    for (int i = t; i < (49 + 95) * 16; i += 256) {
        int rr = i >> 4, c4 = (i & 15) * 4;
        if (rr < 49)
            *(float4*)&rph_st[rr][c4] = *(const float4*)&rel_pos_h[(size_t)(hmin + rr) * HD + c4];
        else
            *(float4*)&rpw_st[rr - 49][c4] = *(const float4*)&rel_pos_w[(size_t)(rr - 49) * HD + c4];
    }
    __syncthreads();
    {
        const int ti = t >> 2, sub = t & 3;
        const int ll = l0 + ti;
        const int hh = ll / WG, ww = ll % WG;
        const int hoff = hh - hmin;
        for (int ko = sub; ko < 96; ko += 4) {
            bool ish = ko < 48;
            int kk = ish ? ko : ko - 48;
            const float* br = ish ? &rph_st[hoff + 47 - kk][0] : &rpw_st[ww + 47 - kk][0];
            float s = 0.f;
            #pragma unroll
            for (int c = 0; c < HD; c += 4) {
                float4 a = *(const float4*)&qf32[ti][c];
                float4 b = *(const float4*)&br[c];
                s += a.x * b.x + a.y * b.y + a.z * b.z + a.w * b.w;
            }
            s *= 8.0f;   // q held as q*2^-3; exact rescale
            if (ish) outh[ti][kk] = f2b(s);
            else     outw[ti][2 + kk] = f2b(s);
        }
    }
    __syncthreads();
    #pragma unroll
    for (int p = 0; p < 2; ++p) {
        int i = t + p * 256;
        int r2 = i >> 3, c8 = (i & 7) * 8;
        *(bf16x8*)&q_ext[((size_t)h * LTOK + l0 + r2) * EXT2 + 64 + c8] =
            *(const bf16x8*)&outw[r2][c8];
    }
    for (int i = t; i < 384; i += 256) {
        int r2 = i / 6, c8 = (i % 6) * 8;
        *(bf16x8*)&relh_g[((size_t)h * LTOK + l0 + r2) * WG + c8] =
            *(const bf16x8*)&outh[r2][c8];
    }
}

// --------------------------- split-K flash attention -----------------------
// grid (18, 12, 2), 256 thr / 4 waves. o_part FP16 lane-major NT. setprio.
__global__ __launch_bounds__(256, 3) void attn_kernel(
    const short* __restrict__ q_ext, const short* __restrict__ kb,
    const short* __restrict__ vT, const short* __restrict__ relh_g,
    _Float16* __restrict__ o_part, float* __restrict__ lsum_g)
{
    __shared__ short ks[64][136];
    __shared__ short vs[64][72];
    __shared__ short rh[128][56];

    const int qblk = blockIdx.x;
    const int n = blockIdx.y;
    const int sp = blockIdx.z;
    const int q0 = qblk * 128;
    const int key_base = sp * KPS;
    const int tid = threadIdx.x;
    const int w = tid >> 6, l = tid & 63;
    const int lm = l & 15, g = l >> 4;
    const int lk = g * 8;

    const short* qeh = q_ext + (size_t)n * LTOK * EXT2;
    const short* kh  = kb + (size_t)n * LTOK * HD;
    const short* vh  = vT + (size_t)n * HD * LTOK;

    bf16x8 qf[2][4];
    #pragma unroll
    for (int t = 0; t < 2; ++t)
        #pragma unroll
        for (int kk = 0; kk < 4; ++kk)
            qf[t][kk] = *(const bf16x8*)&qeh[(size_t)(q0 + w * 32 + t * 16 + lm) * EXT2 + kk * 32 + lk];

    for (int i = tid; i < 128 * 6; i += 256) {
        int row = i / 6, c8 = (i % 6) * 8;
        *(bf16x8*)&rh[row][c8] =
            *(const bf16x8*)&relh_g[((size_t)n * LTOK + q0 + row) * WG + c8];
    }
    {
        const bf16x8 z8 = {0, 0, 0, 0, 0, 0, 0, 0};
        #pragma unroll
        for (int p = 0; p < 2; ++p) {
            int i = tid + p * 256;
            int row = i >> 3, c8 = (i & 7) * 8;
            *(bf16x8*)&ks[row][64 + c8] = z8;
        }
    }
    const short ONE = f2b(1.0f);
    int kap = 0, prev_wi = 66;
    if (tid < 64) {
        int f_ = tid >> 4, m_ = tid & 15;
        kap = 32 * (f_ >> 1) + 8 * (m_ >> 2) + 4 * (f_ & 1) + (m_ & 3);
        prev_wi = 66 + (key_base + kap) % WG;
    }

    bf16x8 kreg[2], vreg[2];
    #define ISSUE_LOADS(kt_)  do {                                              \
        const int key0_ = key_base + (kt_) * 64;                                \
        _Pragma("unroll")                                                       \
        for (int p = 0; p < 2; ++p) {                                           \
            int fl_ = tid + p * 256;                                            \
            int rho_ = fl_ >> 3, c8_ = (fl_ & 7) * 8;                           \
            int f_ = rho_ >> 4, m_ = rho_ & 15;                                 \
            int kap_ = 32 * (f_ >> 1) + 8 * (m_ >> 2) + 4 * (f_ & 1) + (m_ & 3);\
            kreg[p] = *(const bf16x8*)&kh[(size_t)(key0_ + kap_) * HD + c8_];   \
        }                                                                       \
        _Pragma("unroll")                                                       \
        for (int p = 0; p < 2; ++p) {                                           \
            int fl_ = tid + p * 256;                                            \
            int row_ = fl_ >> 3, c8_ = (fl_ & 7) * 8;                           \
            vreg[p] = *(const bf16x8*)&vh[(size_t)row_ * LTOK + key0_ + c8_];   \
        }                                                                       \
    } while (0)

    float lsum[2] = {0.f, 0.f};
    f32x4 oacc[2][4];
    const f32x4 zf = {0.f, 0.f, 0.f, 0.f};
    #pragma unroll
    for (int t = 0; t < 2; ++t)
        #pragma unroll
        for (int d = 0; d < 4; ++d) oacc[t][d] = zf;

    ISSUE_LOADS(0);

    for (int kt = 0; kt < NT; ++kt) {
        const int key0 = key_base + kt * 64;
        const int A = key0 / WG;
        const int T = WG * (A + 1);
        __syncthreads();
        #pragma unroll
        for (int p = 0; p < 2; ++p) {
            int fl = tid + p * 256;
            int rho = fl >> 3, c8 = (fl & 7) * 8;
            *(bf16x8*)&ks[rho][c8] = kreg[p];
        }
        #pragma unroll
        for (int p = 0; p < 2; ++p) {
            int fl = tid + p * 256;
            int row = fl >> 3, c8 = (fl & 7) * 8;
            *(bf16x8*)&vs[row][c8] = vreg[p];
        }
        if (tid < 64) {
            int key = key0 + kap;
            ks[tid][64] = (key < T) ? ONE : (short)0;
            ks[tid][65] = (key < T) ? (short)0 : ONE;
            ks[tid][prev_wi] = 0;
            int wcol = 66 + key % WG;
            ks[tid][wcol] = ONE;
            prev_wi = wcol;
        }
        if (kt + 1 < NT) { ISSUE_LOADS(kt + 1); }
        __builtin_amdgcn_sched_barrier(0);
        __syncthreads();

        if (g == 0) {
            #pragma unroll
            for (int t = 0; t < 2; ++t) {
                int row = w * 32 + t * 16 + lm;
                qf[t][2][0] = rh[row][A];
                qf[t][2][1] = rh[row][A + 1];
            }
        }

        f32x4 st[2][4];
        #pragma unroll
        for (int t = 0; t < 2; ++t)
            #pragma unroll
            for (int f = 0; f < 4; ++f) st[t][f] = zf;
        __builtin_amdgcn_s_setprio(1);
        #pragma unroll
        for (int f = 0; f < 4; ++f)
            #pragma unroll
            for (int kk = 0; kk < 4; ++kk) {
                bf16x8 kf = *(const bf16x8*)&ks[f * 16 + lm][kk * 32 + lk];
                st[0][f] = __builtin_amdgcn_mfma_f32_16x16x32_bf16(kf, qf[0][kk], st[0][f], 0, 0, 0);
                st[1][f] = __builtin_amdgcn_mfma_f32_16x16x32_bf16(kf, qf[1][kk], st[1][f], 0, 0, 0);
            }
        __builtin_amdgcn_s_setprio(0);
        bf16x8 pf[2][2];
        #pragma unroll
        for (int t = 0; t < 2; ++t)
            #pragma unroll
            for (int f = 0; f < 4; ++f)
                #pragma unroll
                for (int r = 0; r < 4; ++r) {
                    float p = __expf(st[t][f][r]);
                    lsum[t] += p;
                    pf[t][f >> 1][(f & 1) * 4 + r] = f2b(p);
                }
        __builtin_amdgcn_s_setprio(1);
        #pragma unroll
        for (int kk = 0; kk < 2; ++kk)
            #pragma unroll
            for (int d = 0; d < 4; ++d) {
                bf16x8 vf = *(const bf16x8*)&vs[d * 16 + lm][kk * 32 + lk];
                oacc[0][d] = __builtin_amdgcn_mfma_f32_16x16x32_bf16(pf[0][kk], vf, oacc[0][d], 0, 0, 0);
                oacc[1][d] = __builtin_amdgcn_mfma_f32_16x16x32_bf16(pf[1][kk], vf, oacc[1][d], 0, 0, 0);
            }
        __builtin_amdgcn_s_setprio(0);
    }
    #undef ISSUE_LOADS

    // lane-major fp16 unnormalized partials (NT 8B vector stores, coalesced)
    size_t pbase = (((size_t)n * NQB2 + qblk) * NSPLIT + sp) * (128 * 64);
    #pragma unroll
    for (int t = 0; t < 2; ++t)
        #pragma unroll
        for (int d = 0; d < 4; ++d) {
            f16x4 hv;
            #pragma unroll
            for (int r = 0; r < 4; ++r) hv[r] = (_Float16)oacc[t][d][r];
            __builtin_nontemporal_store(hv,
                (f16x4*)&o_part[pbase + (size_t)(((w * 2 + t) * 4 + d) * 256) + l * 4]);
        }
    size_t lb = (((size_t)n * NQB2 + qblk) * NSPLIT + sp) * 128;
    #pragma unroll
    for (int t = 0; t < 2; ++t) {
        float s = lsum[t];
        s += __shfl_xor(s, 16);
        s += __shfl_xor(s, 32);
        if (l < 16) lsum_g[lb + w * 32 + t * 16 + l] = s;
    }
}

// --------------------------- split-K combine (2 fp16 partials) -------------
__global__ __launch_bounds__(256) void combine_kernel(
    const _Float16* __restrict__ o_part, const float* __restrict__ lsum_g,
    short* __restrict__ o)
{
    __shared__ short ost[128][72];
    const int qblk = blockIdx.x, h = blockIdx.y;
    const int tid = threadIdx.x;
    const int w = tid >> 6, l = tid & 63;
    const int lm = l & 15, g = l >> 4;
    size_t sb = ((size_t)h * NQB2 + qblk) * NSPLIT;

    float inv[2][4];
    #pragma unroll
    for (int t = 0; t < 2; ++t)
        #pragma unroll
        for (int r = 0; r < 4; ++r) {
            int row = w * 32 + t * 16 + g * 4 + r;
            float ls = 0.f;
            #pragma unroll
            for (int s = 0; s < NSPLIT; ++s)
                ls += lsum_g[(sb + s) * 128 + row];
            inv[t][r] = 1.0f / ls;
        }
    #pragma unroll
    for (int t = 0; t < 2; ++t)
        #pragma unroll
        for (int d = 0; d < 4; ++d) {
            size_t off = (size_t)(((w * 2 + t) * 4 + d) * 256) + l * 4;
            float acc[4] = {0.f, 0.f, 0.f, 0.f};
            #pragma unroll
            for (int s = 0; s < NSPLIT; ++s) {
                f16x4 hv = nt_load_h4(&o_part[(sb + s) * 8192 + off]);
                #pragma unroll
                for (int r = 0; r < 4; ++r) acc[r] += (float)hv[r];
            }
            #pragma unroll
            for (int r = 0; r < 4; ++r)
                ost[w * 32 + t * 16 + g * 4 + r][d * 16 + lm] = f2b(acc[r] * inv[t][r]);
        }
    __syncthreads();
    const int row = tid >> 1, cb = (tid & 1) * 32;
    size_t ob = ((size_t)(qblk * 128 + row)) * DIMC + h * 64 + cb;
    #pragma unroll
    for (int v = 0; v < 4; ++v)
        *(bf16x8*)&o[ob + v * 8] = *(const bf16x8*)&ost[row][cb + v * 8];
}

// ---------------------------------------------------------------------------
extern "C" void kernel_launch(void* const* d_in, const int* in_sizes, int n_in,
                              void* d_out, int out_size, void* d_ws, size_t ws_size,
                              hipStream_t stream) {
    (void)in_sizes; (void)n_in; (void)out_size; (void)ws_size;
    const float* x         = (const float*)d_in[0];
    const float* w_qkv     = (const float*)d_in[1];
    const float* b_qkv     = (const float*)d_in[2];
    const float* w_proj    = (const float*)d_in[3];
    const float* b_proj    = (const float*)d_in[4];
    const float* rel_pos_h = (const float*)d_in[5];
    const float* rel_pos_w = (const float*)d_in[6];
    float* out = (float*)d_out;

    // region0: qkv_raw + xb + wqkvT (dead after split_rope) aliased by
    // o_part (fp16, 12*18*2*8192 halfs = 7.1 MB <= 28.3 MB region).
    float* qkv_raw   = (float*)d_ws;                              // 5,308,416 f32
    short* xb        = (short*)(qkv_raw + (size_t)LTOK * QKVN);   // 1,769,472 bf16
    short* wqkvT     = xb + (size_t)LTOK * DIMC;                  // 1,769,472 bf16
    float* cost      = (float*)(wqkvT + (size_t)QKVN * DIMC);     // 73,728 f32
    float* sint      = cost + (size_t)LTOK * 32;                  // 73,728 f32
    _Float16* o_part = (_Float16*)qkv_raw;                        // alias
    // region1: live through the whole pipeline
    short* wprojT  = (short*)(sint + (size_t)LTOK * 32);          // 589,824 bf16
    short* q_ext   = wprojT + (size_t)DIMC * DIMC;                // NH*L*128
    short* kb      = q_ext + (size_t)NH * LTOK * EXT2;            // NH*L*64
    short* vTb     = kb + (size_t)NH * LTOK * HD;                 // NH*L*64
    short* ob      = vTb + (size_t)NH * LTOK * HD;                // L*768
    short* relh_g  = ob + (size_t)LTOK * DIMC;                    // NH*L*48
    float* lsum_g  = (float*)(relh_g + (size_t)NH * LTOK * WG);   // 12*18*2*128 f32

    prep_kernel<<<dim3(NB_ROPE + NB_CAST + NB_TQKV + NB_TPRJ), 256, 0, stream>>>(
        x, w_qkv, w_proj, cost, sint, xb, wqkvT, wprojT);

    gemm_bf16_64x128_kernel<<<dim3(QKVN / 128, LTOK / 64), 256, 0, stream>>>(
        xb, wqkvT, b_qkv, qkv_raw, LTOK, QKVN, DIMC);

    split_rope_relbias_kernel<<<dim3(LTOK / 64, NH), 256, 0, stream>>>(
        qkv_raw, cost, sint, rel_pos_h, rel_pos_w, q_ext, kb, vTb, relh_g);

    attn_kernel<<<dim3(NQB2, NH, NSPLIT), 256, 0, stream>>>(
        q_ext, kb, vTb, relh_g, o_part, lsum_g);

    combine_kernel<<<dim3(NQB2, NH), 256, 0, stream>>>(o_part, lsum_g, ob);

    gemm32x64_kernel<<<dim3(DIMC / 64, LTOK / 32), 256, 0, stream>>>(
        ob, wprojT, b_proj, out, LTOK, DIMC, DIMC);
}

// Round 25
// 97.298 us; speedup vs baseline: 1.0126x; 1.0126x over previous
//
#include <hip/hip_runtime.h>
#include <hip/hip_bf16.h>

// ---------------------------------------------------------------------------
// TRTAttention round 25 (FINAL = r23 best, 97.3us): NSPLIT=3 confirmed
// optimal by full sweep (2:98.5 / 3:97.3 / 4:112 / 6:128). Pipeline:
// prep(merged rope|cast|transposes) -> 64x128 QKV gemm -> fused
// split_rope+relbias -> split-K flash attn (EXT2=128 one-hot bias fold,
// fixed-max softmax, permuted-K in-lane PV, fp16 lane-major NT o_part,
// setprio, (256,3) no-spill) -> combine -> 32x64 proj gemm.
// ---------------------------------------------------------------------------

typedef short bf16x8 __attribute__((ext_vector_type(8)));
typedef float f32x4  __attribute__((ext_vector_type(4)));
typedef _Float16 f16x4 __attribute__((ext_vector_type(4)));

namespace {
constexpr int LTOK = 2304;
constexpr int DIMC = 768;
constexpr int NH   = 12;
constexpr int HD   = 64;
constexpr int WG   = 48;
constexpr int QKVN = 2304;
constexpr int EXT2 = 128;             // 64 K | 2 oh_h | 48 oh_w | 14 zero
constexpr int NSPLIT = 3;
constexpr int KPS  = LTOK / NSPLIT;   // 768
constexpr int NT   = KPS / 64;        // 12
constexpr int NQB2 = LTOK / 128;      // 18
constexpr float SCALE = 0.125f;
// merged prep kernel block ranges
constexpr int NB_ROPE = (LTOK * 32) / 256;          // 288
constexpr int NB_CAST = (LTOK * DIMC / 8) / 256;    // 864
constexpr int NB_TQKV = (QKVN / 32) * (DIMC / 32);  // 1728
constexpr int NB_TPRJ = (DIMC / 32) * (DIMC / 32);  // 576
}

__device__ __forceinline__ short f2b(float f) {
    __hip_bfloat16 h = __float2bfloat16(f);
    return *reinterpret_cast<short*>(&h);
}
__device__ __forceinline__ float b2f(short s) {
    return __uint_as_float(((unsigned)(unsigned short)s) << 16);
}
__device__ __forceinline__ void load16_to_lds(const short* g, short* l) {
    __builtin_amdgcn_global_load_lds(
        (__attribute__((address_space(1))) void*)g,
        (__attribute__((address_space(3))) void*)l,
        16, 0, 0);
}
__device__ __forceinline__ f16x4 nt_load_h4(const _Float16* p) {
    return __builtin_nontemporal_load((const f16x4*)p);
}

// ---------------- merged prep: rope tables | cast | 2 transposes -----------
__global__ __launch_bounds__(256) void prep_kernel(
    const float* __restrict__ x, const float* __restrict__ w_qkv,
    const float* __restrict__ w_proj,
    float* __restrict__ cost, float* __restrict__ sint,
    short* __restrict__ xb, short* __restrict__ wqkvT, short* __restrict__ wprojT)
{
    __shared__ float ts[32][36];
    const int b = blockIdx.x;
    const int t = threadIdx.x;
    if (b < NB_ROPE) {
        int idx = b * 256 + t;
        int j = idx & 31;
        int l = idx >> 5;
        float tt = (j < 16) ? (float)(l % WG) : (float)(l / WG);
        int fi = j & 15;
        float freq = powf(10000.0f, -(float)fi / 16.0f);
        float ang = tt * freq;
        cost[idx] = cosf(ang);
        sint[idx] = sinf(ang);
    } else if (b < NB_ROPE + NB_CAST) {
        int i = (b - NB_ROPE) * 256 + t;
        float4 a = ((const float4*)x)[2 * i];
        float4 bb = ((const float4*)x)[2 * i + 1];
        bf16x8 o;
        o[0] = f2b(a.x); o[1] = f2b(a.y); o[2] = f2b(a.z); o[3] = f2b(a.w);
        o[4] = f2b(bb.x); o[5] = f2b(bb.y); o[6] = f2b(bb.z); o[7] = f2b(bb.w);
        ((bf16x8*)xb)[i] = o;
    } else {
        const float* in;
        short* out;
        int R, C, c0, r0;
        if (b < NB_ROPE + NB_CAST + NB_TQKV) {
            int flat = b - NB_ROPE - NB_CAST;
            in = w_qkv; out = wqkvT; R = DIMC; C = QKVN;
            c0 = (flat % (QKVN / 32)) * 32;
            r0 = (flat / (QKVN / 32)) * 32;
        } else {
            int flat = b - NB_ROPE - NB_CAST - NB_TQKV;
            in = w_proj; out = wprojT; R = DIMC; C = DIMC;
            c0 = (flat % (DIMC / 32)) * 32;
            r0 = (flat / (DIMC / 32)) * 32;
        }
        {
            int r = t >> 3, cb = (t & 7) * 4;
            float4 v = *(const float4*)&in[(size_t)(r0 + r) * C + c0 + cb];
            ts[r][cb] = v.x; ts[r][cb + 1] = v.y; ts[r][cb + 2] = v.z; ts[r][cb + 3] = v.w;
        }
        __syncthreads();
        {
            int oc = t >> 3, rb = (t & 7) * 4;
            short4 s;
            s.x = f2b(ts[rb][oc]);     s.y = f2b(ts[rb + 1][oc]);
            s.z = f2b(ts[rb + 2][oc]); s.w = f2b(ts[rb + 3][oc]);
            *(short4*)&out[(size_t)(c0 + oc) * R + r0 + rb] = s;
        }
    }
}

// ------- bf16 MFMA GEMM 64x128 tile + bias, 256 thr / 4 waves (QKV) --------
__global__ __launch_bounds__(256) void gemm_bf16_64x128_kernel(
    const short* __restrict__ A, const short* __restrict__ Bt,
    const float* __restrict__ bias, float* __restrict__ C,
    int M, int N, int K)
{
    __shared__ short As[64 * 64];
    __shared__ short Bs[128 * 64];
    const int tid = threadIdx.x;
    const int bm = blockIdx.y * 64, bn = blockIdx.x * 128;
    const int w = tid >> 6, l = tid & 63;
    const int lm = l & 15, lk = (l >> 4) * 8;

    f32x4 acc[4][2];
    const f32x4 zf = {0.f, 0.f, 0.f, 0.f};
    #pragma unroll
    for (int m = 0; m < 4; ++m)
        #pragma unroll
        for (int n = 0; n < 2; ++n) acc[m][n] = zf;

    for (int k0 = 0; k0 < K; k0 += 64) {
        __syncthreads();
        #pragma unroll
        for (int p = 0; p < 2; ++p) {      // As: 512 loads
            int f = tid + p * 256;
            int row = f >> 3, c8 = (f & 7) * 8;
            load16_to_lds(&A[(size_t)(bm + row) * K + k0 + c8], &As[f * 8]);
        }
        #pragma unroll
        for (int p = 0; p < 4; ++p) {      // Bs: 1024 loads
            int f = tid + p * 256;
            int row = f >> 3, c8 = (f & 7) * 8;
            load16_to_lds(&Bt[(size_t)(bn + row) * K + k0 + c8], &Bs[f * 8]);
        }
        __syncthreads();
        #pragma unroll
        for (int kh = 0; kh < 2; ++kh) {
            bf16x8 a[4], b[2];
            #pragma unroll
            for (int m = 0; m < 4; ++m)
                a[m] = *(const bf16x8*)&As[(m * 16 + lm) * 64 + kh * 32 + lk];
            #pragma unroll
            for (int n = 0; n < 2; ++n)
                b[n] = *(const bf16x8*)&Bs[(w * 32 + n * 16 + lm) * 64 + kh * 32 + lk];
            #pragma unroll
            for (int m = 0; m < 4; ++m)
                #pragma unroll
                for (int n = 0; n < 2; ++n)
                    acc[m][n] = __builtin_amdgcn_mfma_f32_16x16x32_bf16(a[m], b[n], acc[m][n], 0, 0, 0);
        }
    }
    const int orow = (l >> 4) * 4;
    #pragma unroll
    for (int m = 0; m < 4; ++m) {
        #pragma unroll
        for (int n = 0; n < 2; ++n) {
            int col = bn + w * 32 + n * 16 + lm;
            float bv = bias[col];
            #pragma unroll
            for (int r = 0; r < 4; ++r) {
                int row = bm + m * 16 + orow + r;
                C[(size_t)row * N + col] = acc[m][n][r] + bv;
            }
        }
    }
}

// ------- bf16 MFMA GEMM 32x64 tile + bias, 256 thr / 4 waves (proj) --------
__global__ __launch_bounds__(256) void gemm32x64_kernel(
    const short* __restrict__ A, const short* __restrict__ Bt,
    const float* __restrict__ bias, float* __restrict__ C,
    int M, int N, int K)
{
    __shared__ short As[32 * 64];
    __shared__ short Bs[64 * 64];
    const int tid = threadIdx.x;
    const int bm = blockIdx.y * 32, bn = blockIdx.x * 64;
    const int w = tid >> 6, l = tid & 63;
    const int lm = l & 15, lk = (l >> 4) * 8;

    f32x4 acc[2];
    const f32x4 zf = {0.f, 0.f, 0.f, 0.f};
    acc[0] = zf; acc[1] = zf;

    for (int k0 = 0; k0 < K; k0 += 64) {
        __syncthreads();
        {
            int row = tid >> 3, c8 = (tid & 7) * 8;   // As: 256 loads
            load16_to_lds(&A[(size_t)(bm + row) * K + k0 + c8], &As[tid * 8]);
        }
        #pragma unroll
        for (int p = 0; p < 2; ++p) {                 // Bs: 512 loads
            int f = tid + p * 256;
            int row = f >> 3, c8 = (f & 7) * 8;
            load16_to_lds(&Bt[(size_t)(bn + row) * K + k0 + c8], &Bs[f * 8]);
        }
        __syncthreads();
        #pragma unroll
        for (int kh = 0; kh < 2; ++kh) {
            bf16x8 a[2], b;
            #pragma unroll
            for (int m = 0; m < 2; ++m)
                a[m] = *(const bf16x8*)&As[(m * 16 + lm) * 64 + kh * 32 + lk];
            b = *(const bf16x8*)&Bs[(w * 16 + lm) * 64 + kh * 32 + lk];
            #pragma unroll
            for (int m = 0; m < 2; ++m)
                acc[m] = __builtin_amdgcn_mfma_f32_16x16x32_bf16(a[m], b, acc[m], 0, 0, 0);
        }
    }
    const int orow = (l >> 4) * 4;
    #pragma unroll
    for (int m = 0; m < 2; ++m) {
        int col = bn + w * 16 + lm;
        float bv = bias[col];
        #pragma unroll
        for (int r = 0; r < 4; ++r) {
            int row = bm + m * 16 + orow + r;
            C[(size_t)row * N + col] = acc[m][r] + bv;
        }
    }
}

// ------ FUSED split qkv + rope + relbias -> q_ext (full), kb, vT, relh_g ---
__global__ __launch_bounds__(256) void split_rope_relbias_kernel(
    const float* __restrict__ qkv_raw,
    const float* __restrict__ cost, const float* __restrict__ sint,
    const float* __restrict__ rel_pos_h, const float* __restrict__ rel_pos_w,
    short* __restrict__ q_ext, short* __restrict__ kb, short* __restrict__ vT,
    short* __restrict__ relh_g)
{
    __shared__ short vt_s[64][72];
    __shared__ float qf32[64][68];
    __shared__ float rph_st[49][68];
    __shared__ float rpw_st[95][68];
    __shared__ short outw[64][64];
    __shared__ short outh[64][48];

    const int h = blockIdx.y;
    const int l0 = blockIdx.x * 64;
    const int hmin = l0 / WG;
    const int t = threadIdx.x;
    const int tok = t >> 2, dq = (t & 3) * 16;
    const int l = l0 + tok;
    const float* row = qkv_raw + (size_t)l * QKVN + h * HD;

    bf16x8 qe[2], kv[2];
    #pragma unroll
    for (int i = 0; i < 16; i += 4) {
        int d = dq + i;
        float4 tq = *(const float4*)&row[d];
        float4 tk = *(const float4*)&row[DIMC + d];
        float4 tv = *(const float4*)&row[2 * DIMC + d];
        float2 c01 = *(const float2*)&cost[l * 32 + d / 2];
        float2 s01 = *(const float2*)&sint[l * 32 + d / 2];
        float q0 = tq.x * c01.x - tq.y * s01.x;
        float q1 = tq.x * s01.x + tq.y * c01.x;
        float q2 = tq.z * c01.y - tq.w * s01.y;
        float q3 = tq.z * s01.y + tq.w * c01.y;
        qe[i >> 3][(i & 7) + 0] = f2b(q0 * SCALE);
        qe[i >> 3][(i & 7) + 1] = f2b(q1 * SCALE);
        qe[i >> 3][(i & 7) + 2] = f2b(q2 * SCALE);
        qe[i >> 3][(i & 7) + 3] = f2b(q3 * SCALE);
        kv[i >> 3][(i & 7) + 0] = f2b(tk.x * c01.x - tk.y * s01.x);
        kv[i >> 3][(i & 7) + 1] = f2b(tk.x * s01.x + tk.y * c01.x);
        kv[i >> 3][(i & 7) + 2] = f2b(tk.z * c01.y - tk.w * s01.y);
        kv[i >> 3][(i & 7) + 3] = f2b(tk.z * s01.y + tk.w * c01.y);
        vt_s[d + 0][tok] = f2b(tv.x);
        vt_s[d + 1][tok] = f2b(tv.y);
        vt_s[d + 2][tok] = f2b(tv.z);
        vt_s[d + 3][tok] = f2b(tv.w);
    }
    size_t kbase = ((size_t)h * LTOK + l) * HD + dq;
    *(bf16x8*)&kb[kbase]     = kv[0];
    *(bf16x8*)&kb[kbase + 8] = kv[1];
    size_t ebase = ((size_t)h * LTOK + l) * EXT2 + dq;
    *(bf16x8*)&q_ext[ebase]     = qe[0];
    *(bf16x8*)&q_ext[ebase + 8] = qe[1];
    #pragma unroll
    for (int i = 0; i < 8; ++i) {
        qf32[tok][dq + i]     = b2f(qe[0][i]);
        qf32[tok][dq + 8 + i] = b2f(qe[1][i]);
    }
    {
        const bf16x8 z8 = {0, 0, 0, 0, 0, 0, 0, 0};
        ((bf16x8*)outw)[t] = z8;
        ((bf16x8*)outw)[t + 256] = z8;
    }
    __syncthreads();
    {
        const int drow = t >> 2, lq = (t & 3) * 16;
        bf16x8 v0 = *(bf16x8*)&vt_s[drow][lq];
        bf16x8 v1 = *(bf16x8*)&vt_s[drow][lq + 8];
        size_t vbase = ((size_t)h * HD + drow) * LTOK + l0 + lq;
        *(bf16x8*)&vT[vbase]     = v0;
        *(bf16x8*)&vT[vbase + 8] = v1;
    }
    for (int i = t; i < (49 + 95) * 16; i += 256) {
        int rr = i >> 4, c4 = (i & 15) * 4;
        if (rr < 49)
            *(float4*)&rph_st[rr][c4] = *(const float4*)&rel_pos_h[(size_t)(hmin + rr) * HD + c4];
        else
            *(float4*)&rpw_st[rr - 49][c4] = *(const float4*)&rel_pos_w[(size_t)(rr - 49) * HD + c4];
    }
    __syncthreads();
    {
        const int ti = t >> 2, sub = t & 3;
        const int ll = l0 + ti;
        const int hh = ll / WG, ww = ll % WG;
        const int hoff = hh - hmin;
        for (int ko = sub; ko < 96; ko += 4) {
            bool ish = ko < 48;
            int kk = ish ? ko : ko - 48;
            const float* br = ish ? &rph_st[hoff + 47 - kk][0] : &rpw_st[ww + 47 - kk][0];
            float s = 0.f;
            #pragma unroll
            for (int c = 0; c < HD; c += 4) {
                float4 a = *(const float4*)&qf32[ti][c];
                float4 b = *(const float4*)&br[c];
                s += a.x * b.x + a.y * b.y + a.z * b.z + a.w * b.w;
            }
            s *= 8.0f;   // q held as q*2^-3; exact rescale
            if (ish) outh[ti][kk] = f2b(s);
            else     outw[ti][2 + kk] = f2b(s);
        }
    }
    __syncthreads();
    #pragma unroll
    for (int p = 0; p < 2; ++p) {
        int i = t + p * 256;
        int r2 = i >> 3, c8 = (i & 7) * 8;
        *(bf16x8*)&q_ext[((size_t)h * LTOK + l0 + r2) * EXT2 + 64 + c8] =
            *(const bf16x8*)&outw[r2][c8];
    }
    for (int i = t; i < 384; i += 256) {
        int r2 = i / 6, c8 = (i % 6) * 8;
        *(bf16x8*)&relh_g[((size_t)h * LTOK + l0 + r2) * WG + c8] =
            *(const bf16x8*)&outh[r2][c8];
    }
}

// --------------------------- split-K flash attention -----------------------
// grid (18, 12, 3), 256 thr / 4 waves. o_part FP16 lane-major NT. setprio.
__global__ __launch_bounds__(256, 3) void attn_kernel(
    const short* __restrict__ q_ext, const short* __restrict__ kb,
    const short* __restrict__ vT, const short* __restrict__ relh_g,
    _Float16* __restrict__ o_part, float* __restrict__ lsum_g)
{
    __shared__ short ks[64][136];
    __shared__ short vs[64][72];
    __shared__ short rh[128][56];

    const int qblk = blockIdx.x;
    const int n = blockIdx.y;
    const int sp = blockIdx.z;
    const int q0 = qblk * 128;
    const int key_base = sp * KPS;
    const int tid = threadIdx.x;
    const int w = tid >> 6, l = tid & 63;
    const int lm = l & 15, g = l >> 4;
    const int lk = g * 8;

    const short* qeh = q_ext + (size_t)n * LTOK * EXT2;
    const short* kh  = kb + (size_t)n * LTOK * HD;
    const short* vh  = vT + (size_t)n * HD * LTOK;

    bf16x8 qf[2][4];
    #pragma unroll
    for (int t = 0; t < 2; ++t)
        #pragma unroll
        for (int kk = 0; kk < 4; ++kk)
            qf[t][kk] = *(const bf16x8*)&qeh[(size_t)(q0 + w * 32 + t * 16 + lm) * EXT2 + kk * 32 + lk];

    for (int i = tid; i < 128 * 6; i += 256) {
        int row = i / 6, c8 = (i % 6) * 8;
        *(bf16x8*)&rh[row][c8] =
            *(const bf16x8*)&relh_g[((size_t)n * LTOK + q0 + row) * WG + c8];
    }
    {
        const bf16x8 z8 = {0, 0, 0, 0, 0, 0, 0, 0};
        #pragma unroll
        for (int p = 0; p < 2; ++p) {
            int i = tid + p * 256;
            int row = i >> 3, c8 = (i & 7) * 8;
            *(bf16x8*)&ks[row][64 + c8] = z8;
        }
    }
    const short ONE = f2b(1.0f);
    int kap = 0, prev_wi = 66;
    if (tid < 64) {
        int f_ = tid >> 4, m_ = tid & 15;
        kap = 32 * (f_ >> 1) + 8 * (m_ >> 2) + 4 * (f_ & 1) + (m_ & 3);
        prev_wi = 66 + (key_base + kap) % WG;
    }

    bf16x8 kreg[2], vreg[2];
    #define ISSUE_LOADS(kt_)  do {                                              \
        const int key0_ = key_base + (kt_) * 64;                                \
        _Pragma("unroll")                                                       \
        for (int p = 0; p < 2; ++p) {                                           \
            int fl_ = tid + p * 256;                                            \
            int rho_ = fl_ >> 3, c8_ = (fl_ & 7) * 8;                           \
            int f_ = rho_ >> 4, m_ = rho_ & 15;                                 \
            int kap_ = 32 * (f_ >> 1) + 8 * (m_ >> 2) + 4 * (f_ & 1) + (m_ & 3);\
            kreg[p] = *(const bf16x8*)&kh[(size_t)(key0_ + kap_) * HD + c8_];   \
        }                                                                       \
        _Pragma("unroll")                                                       \
        for (int p = 0; p < 2; ++p) {                                           \
            int fl_ = tid + p * 256;                                            \
            int row_ = fl_ >> 3, c8_ = (fl_ & 7) * 8;                           \
            vreg[p] = *(const bf16x8*)&vh[(size_t)row_ * LTOK + key0_ + c8_];   \
        }                                                                       \
    } while (0)

    float lsum[2] = {0.f, 0.f};
    f32x4 oacc[2][4];
    const f32x4 zf = {0.f, 0.f, 0.f, 0.f};
    #pragma unroll
    for (int t = 0; t < 2; ++t)
        #pragma unroll
        for (int d = 0; d < 4; ++d) oacc[t][d] = zf;

    ISSUE_LOADS(0);

    for (int kt = 0; kt < NT; ++kt) {
        const int key0 = key_base + kt * 64;
        const int A = key0 / WG;
        const int T = WG * (A + 1);
        __syncthreads();
        #pragma unroll
        for (int p = 0; p < 2; ++p) {
            int fl = tid + p * 256;
            int rho = fl >> 3, c8 = (fl & 7) * 8;
            *(bf16x8*)&ks[rho][c8] = kreg[p];
        }
        #pragma unroll
        for (int p = 0; p < 2; ++p) {
            int fl = tid + p * 256;
            int row = fl >> 3, c8 = (fl & 7) * 8;
            *(bf16x8*)&vs[row][c8] = vreg[p];
        }
        if (tid < 64) {
            int key = key0 + kap;
            ks[tid][64] = (key < T) ? ONE : (short)0;
            ks[tid][65] = (key < T) ? (short)0 : ONE;
            ks[tid][prev_wi] = 0;
            int wcol = 66 + key % WG;
            ks[tid][wcol] = ONE;
            prev_wi = wcol;
        }
        if (kt + 1 < NT) { ISSUE_LOADS(kt + 1); }
        __builtin_amdgcn_sched_barrier(0);
        __syncthreads();

        if (g == 0) {
            #pragma unroll
            for (int t = 0; t < 2; ++t) {
                int row = w * 32 + t * 16 + lm;
                qf[t][2][0] = rh[row][A];
                qf[t][2][1] = rh[row][A + 1];
            }
        }

        f32x4 st[2][4];
        #pragma unroll
        for (int t = 0; t < 2; ++t)
            #pragma unroll
            for (int f = 0; f < 4; ++f) st[t][f] = zf;
        __builtin_amdgcn_s_setprio(1);
        #pragma unroll
        for (int f = 0; f < 4; ++f)
            #pragma unroll
            for (int kk = 0; kk < 4; ++kk) {
                bf16x8 kf = *(const bf16x8*)&ks[f * 16 + lm][kk * 32 + lk];
                st[0][f] = __builtin_amdgcn_mfma_f32_16x16x32_bf16(kf, qf[0][kk], st[0][f], 0, 0, 0);
                st[1][f] = __builtin_amdgcn_mfma_f32_16x16x32_bf16(kf, qf[1][kk], st[1][f], 0, 0, 0);
            }
        __builtin_amdgcn_s_setprio(0);
        bf16x8 pf[2][2];
        #pragma unroll
        for (int t = 0; t < 2; ++t)
            #pragma unroll
            for (int f = 0; f < 4; ++f)
                #pragma unroll
                for (int r = 0; r < 4; ++r) {
                    float p = __expf(st[t][f][r]);
                    lsum[t] += p;
                    pf[t][f >> 1][(f & 1) * 4 + r] = f2b(p);
                }
        __builtin_amdgcn_s_setprio(1);
        #pragma unroll
        for (int kk = 0; kk < 2; ++kk)
            #pragma unroll
            for (int d = 0; d < 4; ++d) {
                bf16x8 vf = *(const bf16x8*)&vs[d * 16 + lm][kk * 32 + lk];
                oacc[0][d] = __builtin_amdgcn_mfma_f32_16x16x32_bf16(pf[0][kk], vf, oacc[0][d], 0, 0, 0);
                oacc[1][d] = __builtin_amdgcn_mfma_f32_16x16x32_bf16(pf[1][kk], vf, oacc[1][d], 0, 0, 0);
            }
        __builtin_amdgcn_s_setprio(0);
    }
    #undef ISSUE_LOADS

    // lane-major fp16 unnormalized partials (NT 8B vector stores, coalesced)
    size_t pbase = (((size_t)n * NQB2 + qblk) * NSPLIT + sp) * (128 * 64);
    #pragma unroll
    for (int t = 0; t < 2; ++t)
        #pragma unroll
        for (int d = 0; d < 4; ++d) {
            f16x4 hv;
            #pragma unroll
            for (int r = 0; r < 4; ++r) hv[r] = (_Float16)oacc[t][d][r];
            __builtin_nontemporal_store(hv,
                (f16x4*)&o_part[pbase + (size_t)(((w * 2 + t) * 4 + d) * 256) + l * 4]);
        }
    size_t lb = (((size_t)n * NQB2 + qblk) * NSPLIT + sp) * 128;
    #pragma unroll
    for (int t = 0; t < 2; ++t) {
        float s = lsum[t];
        s += __shfl_xor(s, 16);
        s += __shfl_xor(s, 32);
        if (l < 16) lsum_g[lb + w * 32 + t * 16 + l] = s;
    }
}

// --------------------------- split-K combine (3 fp16 partials) -------------
__global__ __launch_bounds__(256) void combine_kernel(
    const _Float16* __restrict__ o_part, const float* __restrict__ lsum_g,
    short* __restrict__ o)
{
    __shared__ short ost[128][72];
    const int qblk = blockIdx.x, h = blockIdx.y;
    const int tid = threadIdx.x;
    const int w = tid >> 6, l = tid & 63;
    const int lm = l & 15, g = l >> 4;
    size_t sb = ((size_t)h * NQB2 + qblk) * NSPLIT;

    float inv[2][4];
    #pragma unroll
    for (int t = 0; t < 2; ++t)
        #pragma unroll
        for (int r = 0; r < 4; ++r) {
            int row = w * 32 + t * 16 + g * 4 + r;
            float ls = 0.f;
            #pragma unroll
            for (int s = 0; s < NSPLIT; ++s)
                ls += lsum_g[(sb + s) * 128 + row];
            inv[t][r] = 1.0f / ls;
        }
    #pragma unroll
    for (int t = 0; t < 2; ++t)
        #pragma unroll
        for (int d = 0; d < 4; ++d) {
            size_t off = (size_t)(((w * 2 + t) * 4 + d) * 256) + l * 4;
            float acc[4] = {0.f, 0.f, 0.f, 0.f};
            #pragma unroll
            for (int s = 0; s < NSPLIT; ++s) {
                f16x4 hv = nt_load_h4(&o_part[(sb + s) * 8192 + off]);
                #pragma unroll
                for (int r = 0; r < 4; ++r) acc[r] += (float)hv[r];
            }
            #pragma unroll
            for (int r = 0; r < 4; ++r)
                ost[w * 32 + t * 16 + g * 4 + r][d * 16 + lm] = f2b(acc[r] * inv[t][r]);
        }
    __syncthreads();
    const int row = tid >> 1, cb = (tid & 1) * 32;
    size_t ob = ((size_t)(qblk * 128 + row)) * DIMC + h * 64 + cb;
    #pragma unroll
    for (int v = 0; v < 4; ++v)
        *(bf16x8*)&o[ob + v * 8] = *(const bf16x8*)&ost[row][cb + v * 8];
}

// ---------------------------------------------------------------------------
extern "C" void kernel_launch(void* const* d_in, const int* in_sizes, int n_in,
                              void* d_out, int out_size, void* d_ws, size_t ws_size,
                              hipStream_t stream) {
    (void)in_sizes; (void)n_in; (void)out_size; (void)ws_size;
    const float* x         = (const float*)d_in[0];
    const float* w_qkv     = (const float*)d_in[1];
    const float* b_qkv     = (const float*)d_in[2];
    const float* w_proj    = (const float*)d_in[3];
    const float* b_proj    = (const float*)d_in[4];
    const float* rel_pos_h = (const float*)d_in[5];
    const float* rel_pos_w = (const float*)d_in[6];
    float* out = (float*)d_out;

    // region0: qkv_raw + xb + wqkvT (dead after split_rope) aliased by
    // o_part (fp16, 12*18*3*8192 halfs = 10.6 MB <= 28.3 MB region).
    float* qkv_raw   = (float*)d_ws;                              // 5,308,416 f32
    short* xb        = (short*)(qkv_raw + (size_t)LTOK * QKVN);   // 1,769,472 bf16
    short* wqkvT     = xb + (size_t)LTOK * DIMC;                  // 1,769,472 bf16
    float* cost      = (float*)(wqkvT + (size_t)QKVN * DIMC);     // 73,728 f32
    float* sint      = cost + (size_t)LTOK * 32;                  // 73,728 f32
    _Float16* o_part = (_Float16*)qkv_raw;                        // alias
    // region1: live through the whole pipeline
    short* wprojT  = (short*)(sint + (size_t)LTOK * 32);          // 589,824 bf16
    short* q_ext   = wprojT + (size_t)DIMC * DIMC;                // NH*L*128
    short* kb      = q_ext + (size_t)NH * LTOK * EXT2;            // NH*L*64
    short* vTb     = kb + (size_t)NH * LTOK * HD;                 // NH*L*64
    short* ob      = vTb + (size_t)NH * LTOK * HD;                // L*768
    short* relh_g  = ob + (size_t)LTOK * DIMC;                    // NH*L*48
    float* lsum_g  = (float*)(relh_g + (size_t)NH * LTOK * WG);   // 12*18*3*128 f32

    prep_kernel<<<dim3(NB_ROPE + NB_CAST + NB_TQKV + NB_TPRJ), 256, 0, stream>>>(
        x, w_qkv, w_proj, cost, sint, xb, wqkvT, wprojT);

    gemm_bf16_64x128_kernel<<<dim3(QKVN / 128, LTOK / 64), 256, 0, stream>>>(
        xb, wqkvT, b_qkv, qkv_raw, LTOK, QKVN, DIMC);

    split_rope_relbias_kernel<<<dim3(LTOK / 64, NH), 256, 0, stream>>>(
        qkv_raw, cost, sint, rel_pos_h, rel_pos_w, q_ext, kb, vTb, relh_g);

    attn_kernel<<<dim3(NQB2, NH, NSPLIT), 256, 0, stream>>>(
        q_ext, kb, vTb, relh_g, o_part, lsum_g);

    combine_kernel<<<dim3(NQB2, NH), 256, 0, stream>>>(o_part, lsum_g, ob);

    gemm32x64_kernel<<<dim3(DIMC / 64, LTOK / 32), 256, 0, stream>>>(
        ob, wprojT, b_proj, out, LTOK, DIMC, DIMC);
}

// Round 26
// 95.169 us; speedup vs baseline: 1.0353x; 1.0224x over previous
//
#include <hip/hip_runtime.h>
#include <hip/hip_bf16.h>

// ---------------------------------------------------------------------------
// TRTAttention round 26: r25 (97.3) + qkv_raw intermediate stored as FP16
// (21.2 MB fp32 -> 10.6 MB fp16; saves ~21 MB HBM round-trip ~ 3.4us).
// fp16 quantization (2^-12 rel) is ~8x below the bf16 rounding the same
// values get right after rope -> absmax grows ~12% only. All else frozen:
// NSPLIT=3, merged prep, fused split_rope+relbias, EXT2=128 attn + setprio,
// (256,3), fp16 lane-major NT o_part, 64x128 QKV, 32x64 proj.
// ---------------------------------------------------------------------------

typedef short bf16x8 __attribute__((ext_vector_type(8)));
typedef float f32x4  __attribute__((ext_vector_type(4)));
typedef _Float16 f16x4 __attribute__((ext_vector_type(4)));

namespace {
constexpr int LTOK = 2304;
constexpr int DIMC = 768;
constexpr int NH   = 12;
constexpr int HD   = 64;
constexpr int WG   = 48;
constexpr int QKVN = 2304;
constexpr int EXT2 = 128;             // 64 K | 2 oh_h | 48 oh_w | 14 zero
constexpr int NSPLIT = 3;
constexpr int KPS  = LTOK / NSPLIT;   // 768
constexpr int NT   = KPS / 64;        // 12
constexpr int NQB2 = LTOK / 128;      // 18
constexpr float SCALE = 0.125f;
// merged prep kernel block ranges
constexpr int NB_ROPE = (LTOK * 32) / 256;          // 288
constexpr int NB_CAST = (LTOK * DIMC / 8) / 256;    // 864
constexpr int NB_TQKV = (QKVN / 32) * (DIMC / 32);  // 1728
constexpr int NB_TPRJ = (DIMC / 32) * (DIMC / 32);  // 576
}

__device__ __forceinline__ short f2b(float f) {
    __hip_bfloat16 h = __float2bfloat16(f);
    return *reinterpret_cast<short*>(&h);
}
__device__ __forceinline__ float b2f(short s) {
    return __uint_as_float(((unsigned)(unsigned short)s) << 16);
}
__device__ __forceinline__ void load16_to_lds(const short* g, short* l) {
    __builtin_amdgcn_global_load_lds(
        (__attribute__((address_space(1))) void*)g,
        (__attribute__((address_space(3))) void*)l,
        16, 0, 0);
}
__device__ __forceinline__ f16x4 nt_load_h4(const _Float16* p) {
    return __builtin_nontemporal_load((const f16x4*)p);
}

// ---------------- merged prep: rope tables | cast | 2 transposes -----------
__global__ __launch_bounds__(256) void prep_kernel(
    const float* __restrict__ x, const float* __restrict__ w_qkv,
    const float* __restrict__ w_proj,
    float* __restrict__ cost, float* __restrict__ sint,
    short* __restrict__ xb, short* __restrict__ wqkvT, short* __restrict__ wprojT)
{
    __shared__ float ts[32][36];
    const int b = blockIdx.x;
    const int t = threadIdx.x;
    if (b < NB_ROPE) {
        int idx = b * 256 + t;
        int j = idx & 31;
        int l = idx >> 5;
        float tt = (j < 16) ? (float)(l % WG) : (float)(l / WG);
        int fi = j & 15;
        float freq = powf(10000.0f, -(float)fi / 16.0f);
        float ang = tt * freq;
        cost[idx] = cosf(ang);
        sint[idx] = sinf(ang);
    } else if (b < NB_ROPE + NB_CAST) {
        int i = (b - NB_ROPE) * 256 + t;
        float4 a = ((const float4*)x)[2 * i];
        float4 bb = ((const float4*)x)[2 * i + 1];
        bf16x8 o;
        o[0] = f2b(a.x); o[1] = f2b(a.y); o[2] = f2b(a.z); o[3] = f2b(a.w);
        o[4] = f2b(bb.x); o[5] = f2b(bb.y); o[6] = f2b(bb.z); o[7] = f2b(bb.w);
        ((bf16x8*)xb)[i] = o;
    } else {
        const float* in;
        short* out;
        int R, C, c0, r0;
        if (b < NB_ROPE + NB_CAST + NB_TQKV) {
            int flat = b - NB_ROPE - NB_CAST;
            in = w_qkv; out = wqkvT; R = DIMC; C = QKVN;
            c0 = (flat % (QKVN / 32)) * 32;
            r0 = (flat / (QKVN / 32)) * 32;
        } else {
            int flat = b - NB_ROPE - NB_CAST - NB_TQKV;
            in = w_proj; out = wprojT; R = DIMC; C = DIMC;
            c0 = (flat % (DIMC / 32)) * 32;
            r0 = (flat / (DIMC / 32)) * 32;
        }
        {
            int r = t >> 3, cb = (t & 7) * 4;
            float4 v = *(const float4*)&in[(size_t)(r0 + r) * C + c0 + cb];
            ts[r][cb] = v.x; ts[r][cb + 1] = v.y; ts[r][cb + 2] = v.z; ts[r][cb + 3] = v.w;
        }
        __syncthreads();
        {
            int oc = t >> 3, rb = (t & 7) * 4;
            short4 s;
            s.x = f2b(ts[rb][oc]);     s.y = f2b(ts[rb + 1][oc]);
            s.z = f2b(ts[rb + 2][oc]); s.w = f2b(ts[rb + 3][oc]);
            *(short4*)&out[(size_t)(c0 + oc) * R + r0 + rb] = s;
        }
    }
}

// --- bf16 MFMA GEMM 64x128 tile + bias -> FP16 output, 256 thr (QKV) -------
__global__ __launch_bounds__(256) void gemm_bf16_64x128_kernel(
    const short* __restrict__ A, const short* __restrict__ Bt,
    const float* __restrict__ bias, _Float16* __restrict__ C,
    int M, int N, int K)
{
    __shared__ short As[64 * 64];
    __shared__ short Bs[128 * 64];
    const int tid = threadIdx.x;
    const int bm = blockIdx.y * 64, bn = blockIdx.x * 128;
    const int w = tid >> 6, l = tid & 63;
    const int lm = l & 15, lk = (l >> 4) * 8;

    f32x4 acc[4][2];
    const f32x4 zf = {0.f, 0.f, 0.f, 0.f};
    #pragma unroll
    for (int m = 0; m < 4; ++m)
        #pragma unroll
        for (int n = 0; n < 2; ++n) acc[m][n] = zf;

    for (int k0 = 0; k0 < K; k0 += 64) {
        __syncthreads();
        #pragma unroll
        for (int p = 0; p < 2; ++p) {      // As: 512 loads
            int f = tid + p * 256;
            int row = f >> 3, c8 = (f & 7) * 8;
            load16_to_lds(&A[(size_t)(bm + row) * K + k0 + c8], &As[f * 8]);
        }
        #pragma unroll
        for (int p = 0; p < 4; ++p) {      // Bs: 1024 loads
            int f = tid + p * 256;
            int row = f >> 3, c8 = (f & 7) * 8;
            load16_to_lds(&Bt[(size_t)(bn + row) * K + k0 + c8], &Bs[f * 8]);
        }
        __syncthreads();
        #pragma unroll
        for (int kh = 0; kh < 2; ++kh) {
            bf16x8 a[4], b[2];
            #pragma unroll
            for (int m = 0; m < 4; ++m)
                a[m] = *(const bf16x8*)&As[(m * 16 + lm) * 64 + kh * 32 + lk];
            #pragma unroll
            for (int n = 0; n < 2; ++n)
                b[n] = *(const bf16x8*)&Bs[(w * 32 + n * 16 + lm) * 64 + kh * 32 + lk];
            #pragma unroll
            for (int m = 0; m < 4; ++m)
                #pragma unroll
                for (int n = 0; n < 2; ++n)
                    acc[m][n] = __builtin_amdgcn_mfma_f32_16x16x32_bf16(a[m], b[n], acc[m][n], 0, 0, 0);
        }
    }
    const int orow = (l >> 4) * 4;
    #pragma unroll
    for (int m = 0; m < 4; ++m) {
        #pragma unroll
        for (int n = 0; n < 2; ++n) {
            int col = bn + w * 32 + n * 16 + lm;
            float bv = bias[col];
            #pragma unroll
            for (int r = 0; r < 4; ++r) {
                int row = bm + m * 16 + orow + r;
                C[(size_t)row * N + col] = (_Float16)(acc[m][n][r] + bv);
            }
        }
    }
}

// ------- bf16 MFMA GEMM 32x64 tile + bias, 256 thr / 4 waves (proj) --------
__global__ __launch_bounds__(256) void gemm32x64_kernel(
    const short* __restrict__ A, const short* __restrict__ Bt,
    const float* __restrict__ bias, float* __restrict__ C,
    int M, int N, int K)
{
    __shared__ short As[32 * 64];
    __shared__ short Bs[64 * 64];
    const int tid = threadIdx.x;
    const int bm = blockIdx.y * 32, bn = blockIdx.x * 64;
    const int w = tid >> 6, l = tid & 63;
    const int lm = l & 15, lk = (l >> 4) * 8;

    f32x4 acc[2];
    const f32x4 zf = {0.f, 0.f, 0.f, 0.f};
    acc[0] = zf; acc[1] = zf;

    for (int k0 = 0; k0 < K; k0 += 64) {
        __syncthreads();
        {
            int row = tid >> 3, c8 = (tid & 7) * 8;   // As: 256 loads
            load16_to_lds(&A[(size_t)(bm + row) * K + k0 + c8], &As[tid * 8]);
        }
        #pragma unroll
        for (int p = 0; p < 2; ++p) {                 // Bs: 512 loads
            int f = tid + p * 256;
            int row = f >> 3, c8 = (f & 7) * 8;
            load16_to_lds(&Bt[(size_t)(bn + row) * K + k0 + c8], &Bs[f * 8]);
        }
        __syncthreads();
        #pragma unroll
        for (int kh = 0; kh < 2; ++kh) {
            bf16x8 a[2], b;
            #pragma unroll
            for (int m = 0; m < 2; ++m)
                a[m] = *(const bf16x8*)&As[(m * 16 + lm) * 64 + kh * 32 + lk];
            b = *(const bf16x8*)&Bs[(w * 16 + lm) * 64 + kh * 32 + lk];
            #pragma unroll
            for (int m = 0; m < 2; ++m)
                acc[m] = __builtin_amdgcn_mfma_f32_16x16x32_bf16(a[m], b, acc[m], 0, 0, 0);
        }
    }
    const int orow = (l >> 4) * 4;
    #pragma unroll
    for (int m = 0; m < 2; ++m) {
        int col = bn + w * 16 + lm;
        float bv = bias[col];
        #pragma unroll
        for (int r = 0; r < 4; ++r) {
            int row = bm + m * 16 + orow + r;
            C[(size_t)row * N + col] = acc[m][r] + bv;
        }
    }
}

// ------ FUSED split qkv + rope + relbias (reads FP16 qkv) ------------------
__global__ __launch_bounds__(256) void split_rope_relbias_kernel(
    const _Float16* __restrict__ qkv_h,
    const float* __restrict__ cost, const float* __restrict__ sint,
    const float* __restrict__ rel_pos_h, const float* __restrict__ rel_pos_w,
    short* __restrict__ q_ext, short* __restrict__ kb, short* __restrict__ vT,
    short* __restrict__ relh_g)
{
    __shared__ short vt_s[64][72];
    __shared__ float qf32[64][68];
    __shared__ float rph_st[49][68];
    __shared__ float rpw_st[95][68];
    __shared__ short outw[64][64];
    __shared__ short outh[64][48];

    const int h = blockIdx.y;
    const int l0 = blockIdx.x * 64;
    const int hmin = l0 / WG;
    const int t = threadIdx.x;
    const int tok = t >> 2, dq = (t & 3) * 16;
    const int l = l0 + tok;
    const _Float16* row = qkv_h + (size_t)l * QKVN + h * HD;

    bf16x8 qe[2], kv[2];
    #pragma unroll
    for (int i = 0; i < 16; i += 4) {
        int d = dq + i;
        f16x4 tq4 = *(const f16x4*)&row[d];
        f16x4 tk4 = *(const f16x4*)&row[DIMC + d];
        f16x4 tv4 = *(const f16x4*)&row[2 * DIMC + d];
        float tqx = (float)tq4[0], tqy = (float)tq4[1];
        float tqz = (float)tq4[2], tqw = (float)tq4[3];
        float tkx = (float)tk4[0], tky = (float)tk4[1];
        float tkz = (float)tk4[2], tkw = (float)tk4[3];
        float2 c01 = *(const float2*)&cost[l * 32 + d / 2];
        float2 s01 = *(const float2*)&sint[l * 32 + d / 2];
        float q0 = tqx * c01.x - tqy * s01.x;
        float q1 = tqx * s01.x + tqy * c01.x;
        float q2 = tqz * c01.y - tqw * s01.y;
        float q3 = tqz * s01.y + tqw * c01.y;
        qe[i >> 3][(i & 7) + 0] = f2b(q0 * SCALE);
        qe[i >> 3][(i & 7) + 1] = f2b(q1 * SCALE);
        qe[i >> 3][(i & 7) + 2] = f2b(q2 * SCALE);
        qe[i >> 3][(i & 7) + 3] = f2b(q3 * SCALE);
        kv[i >> 3][(i & 7) + 0] = f2b(tkx * c01.x - tky * s01.x);
        kv[i >> 3][(i & 7) + 1] = f2b(tkx * s01.x + tky * c01.x);
        kv[i >> 3][(i & 7) + 2] = f2b(tkz * c01.y - tkw * s01.y);
        kv[i >> 3][(i & 7) + 3] = f2b(tkz * s01.y + tkw * c01.y);
        vt_s[d + 0][tok] = f2b((float)tv4[0]);
        vt_s[d + 1][tok] = f2b((float)tv4[1]);
        vt_s[d + 2][tok] = f2b((float)tv4[2]);
        vt_s[d + 3][tok] = f2b((float)tv4[3]);
    }
    size_t kbase = ((size_t)h * LTOK + l) * HD + dq;
    *(bf16x8*)&kb[kbase]     = kv[0];
    *(bf16x8*)&kb[kbase + 8] = kv[1];
    size_t ebase = ((size_t)h * LTOK + l) * EXT2 + dq;
    *(bf16x8*)&q_ext[ebase]     = qe[0];
    *(bf16x8*)&q_ext[ebase + 8] = qe[1];
    #pragma unroll
    for (int i = 0; i < 8; ++i) {
        qf32[tok][dq + i]     = b2f(qe[0][i]);
        qf32[tok][dq + 8 + i] = b2f(qe[1][i]);
    }
    {
        const bf16x8 z8 = {0, 0, 0, 0, 0, 0, 0, 0};
        ((bf16x8*)outw)[t] = z8;
        ((bf16x8*)outw)[t + 256] = z8;
    }
    __syncthreads();
    {
        const int drow = t >> 2, lq = (t & 3) * 16;
        bf16x8 v0 = *(bf16x8*)&vt_s[drow][lq];
        bf16x8 v1 = *(bf16x8*)&vt_s[drow][lq + 8];
        size_t vbase = ((size_t)h * HD + drow) * LTOK + l0 + lq;
        *(bf16x8*)&vT[vbase]     = v0;
        *(bf16x8*)&vT[vbase + 8] = v1;
    }
    for (int i = t; i < (49 + 95) * 16; i += 256) {
        int rr = i >> 4, c4 = (i & 15) * 4;
        if (rr < 49)
            *(float4*)&rph_st[rr][c4] = *(const float4*)&rel_pos_h[(size_t)(hmin + rr) * HD + c4];
        else
            *(float4*)&rpw_st[rr - 49][c4] = *(const float4*)&rel_pos_w[(size_t)(rr - 49) * HD + c4];
    }
    __syncthreads();
    {
        const int ti = t >> 2, sub = t & 3;
        const int ll = l0 + ti;
        const int hh = ll / WG, ww = ll % WG;
        const int hoff = hh - hmin;
        for (int ko = sub; ko < 96; ko += 4) {
            bool ish = ko < 48;
            int kk = ish ? ko : ko - 48;
            const float* br = ish ? &rph_st[hoff + 47 - kk][0] : &rpw_st[ww + 47 - kk][0];
            float s = 0.f;
            #pragma unroll
            for (int c = 0; c < HD; c += 4) {
                float4 a = *(const float4*)&qf32[ti][c];
                float4 b = *(const float4*)&br[c];
                s += a.x * b.x + a.y * b.y + a.z * b.z + a.w * b.w;
            }
            s *= 8.0f;   // q held as q*2^-3; exact rescale
            if (ish) outh[ti][kk] = f2b(s);
            else     outw[ti][2 + kk] = f2b(s);
        }
    }
    __syncthreads();
    #pragma unroll
    for (int p = 0; p < 2; ++p) {
        int i = t + p * 256;
        int r2 = i >> 3, c8 = (i & 7) * 8;
        *(bf16x8*)&q_ext[((size_t)h * LTOK + l0 + r2) * EXT2 + 64 + c8] =
            *(const bf16x8*)&outw[r2][c8];
    }
    for (int i = t; i < 384; i += 256) {
        int r2 = i / 6, c8 = (i % 6) * 8;
        *(bf16x8*)&relh_g[((size_t)h * LTOK + l0 + r2) * WG + c8] =
            *(const bf16x8*)&outh[r2][c8];
    }
}

// --------------------------- split-K flash attention -----------------------
// grid (18, 12, 3), 256 thr / 4 waves. o_part FP16 lane-major NT. setprio.
__global__ __launch_bounds__(256, 3) void attn_kernel(
    const short* __restrict__ q_ext, const short* __restrict__ kb,
    const short* __restrict__ vT, const short* __restrict__ relh_g,
    _Float16* __restrict__ o_part, float* __restrict__ lsum_g)
{
    __shared__ short ks[64][136];
    __shared__ short vs[64][72];
    __shared__ short rh[128][56];

    const int qblk = blockIdx.x;
    const int n = blockIdx.y;
    const int sp = blockIdx.z;
    const int q0 = qblk * 128;
    const int key_base = sp * KPS;
    const int tid = threadIdx.x;
    const int w = tid >> 6, l = tid & 63;
    const int lm = l & 15, g = l >> 4;
    const int lk = g * 8;

    const short* qeh = q_ext + (size_t)n * LTOK * EXT2;
    const short* kh  = kb + (size_t)n * LTOK * HD;
    const short* vh  = vT + (size_t)n * HD * LTOK;

    bf16x8 qf[2][4];
    #pragma unroll
    for (int t = 0; t < 2; ++t)
        #pragma unroll
        for (int kk = 0; kk < 4; ++kk)
            qf[t][kk] = *(const bf16x8*)&qeh[(size_t)(q0 + w * 32 + t * 16 + lm) * EXT2 + kk * 32 + lk];

    for (int i = tid; i < 128 * 6; i += 256) {
        int row = i / 6, c8 = (i % 6) * 8;
        *(bf16x8*)&rh[row][c8] =
            *(const bf16x8*)&relh_g[((size_t)n * LTOK + q0 + row) * WG + c8];
    }
    {
        const bf16x8 z8 = {0, 0, 0, 0, 0, 0, 0, 0};
        #pragma unroll
        for (int p = 0; p < 2; ++p) {
            int i = tid + p * 256;
            int row = i >> 3, c8 = (i & 7) * 8;
            *(bf16x8*)&ks[row][64 + c8] = z8;
        }
    }
    const short ONE = f2b(1.0f);
    int kap = 0, prev_wi = 66;
    if (tid < 64) {
        int f_ = tid >> 4, m_ = tid & 15;
        kap = 32 * (f_ >> 1) + 8 * (m_ >> 2) + 4 * (f_ & 1) + (m_ & 3);
        prev_wi = 66 + (key_base + kap) % WG;
    }

    bf16x8 kreg[2], vreg[2];
    #define ISSUE_LOADS(kt_)  do {                                              \
        const int key0_ = key_base + (kt_) * 64;                                \
        _Pragma("unroll")                                                       \
        for (int p = 0; p < 2; ++p) {                                           \
            int fl_ = tid + p * 256;                                            \
            int rho_ = fl_ >> 3, c8_ = (fl_ & 7) * 8;                           \
            int f_ = rho_ >> 4, m_ = rho_ & 15;                                 \
            int kap_ = 32 * (f_ >> 1) + 8 * (m_ >> 2) + 4 * (f_ & 1) + (m_ & 3);\
            kreg[p] = *(const bf16x8*)&kh[(size_t)(key0_ + kap_) * HD + c8_];   \
        }                                                                       \
        _Pragma("unroll")                                                       \
        for (int p = 0; p < 2; ++p) {                                           \
            int fl_ = tid + p * 256;                                            \
            int row_ = fl_ >> 3, c8_ = (fl_ & 7) * 8;                           \
            vreg[p] = *(const bf16x8*)&vh[(size_t)row_ * LTOK + key0_ + c8_];   \
        }                                                                       \
    } while (0)

    float lsum[2] = {0.f, 0.f};
    f32x4 oacc[2][4];
    const f32x4 zf = {0.f, 0.f, 0.f, 0.f};
    #pragma unroll
    for (int t = 0; t < 2; ++t)
        #pragma unroll
        for (int d = 0; d < 4; ++d) oacc[t][d] = zf;

    ISSUE_LOADS(0);

    for (int kt = 0; kt < NT; ++kt) {
        const int key0 = key_base + kt * 64;
        const int A = key0 / WG;
        const int T = WG * (A + 1);
        __syncthreads();
        #pragma unroll
        for (int p = 0; p < 2; ++p) {
            int fl = tid + p * 256;
            int rho = fl >> 3, c8 = (fl & 7) * 8;
            *(bf16x8*)&ks[rho][c8] = kreg[p];
        }
        #pragma unroll
        for (int p = 0; p < 2; ++p) {
            int fl = tid + p * 256;
            int row = fl >> 3, c8 = (fl & 7) * 8;
            *(bf16x8*)&vs[row][c8] = vreg[p];
        }
        if (tid < 64) {
            int key = key0 + kap;
            ks[tid][64] = (key < T) ? ONE : (short)0;
            ks[tid][65] = (key < T) ? (short)0 : ONE;
            ks[tid][prev_wi] = 0;
            int wcol = 66 + key % WG;
            ks[tid][wcol] = ONE;
            prev_wi = wcol;
        }
        if (kt + 1 < NT) { ISSUE_LOADS(kt + 1); }
        __builtin_amdgcn_sched_barrier(0);
        __syncthreads();

        if (g == 0) {
            #pragma unroll
            for (int t = 0; t < 2; ++t) {
                int row = w * 32 + t * 16 + lm;
                qf[t][2][0] = rh[row][A];
                qf[t][2][1] = rh[row][A + 1];
            }
        }

        f32x4 st[2][4];
        #pragma unroll
        for (int t = 0; t < 2; ++t)
            #pragma unroll
            for (int f = 0; f < 4; ++f) st[t][f] = zf;
        __builtin_amdgcn_s_setprio(1);
        #pragma unroll
        for (int f = 0; f < 4; ++f)
            #pragma unroll
            for (int kk = 0; kk < 4; ++kk) {
                bf16x8 kf = *(const bf16x8*)&ks[f * 16 + lm][kk * 32 + lk];
                st[0][f] = __builtin_amdgcn_mfma_f32_16x16x32_bf16(kf, qf[0][kk], st[0][f], 0, 0, 0);
                st[1][f] = __builtin_amdgcn_mfma_f32_16x16x32_bf16(kf, qf[1][kk], st[1][f], 0, 0, 0);
            }
        __builtin_amdgcn_s_setprio(0);
        bf16x8 pf[2][2];
        #pragma unroll
        for (int t = 0; t < 2; ++t)
            #pragma unroll
            for (int f = 0; f < 4; ++f)
                #pragma unroll
                for (int r = 0; r < 4; ++r) {
                    float p = __expf(st[t][f][r]);
                    lsum[t] += p;
                    pf[t][f >> 1][(f & 1) * 4 + r] = f2b(p);
                }
        __builtin_amdgcn_s_setprio(1);
        #pragma unroll
        for (int kk = 0; kk < 2; ++kk)
            #pragma unroll
            for (int d = 0; d < 4; ++d) {
                bf16x8 vf = *(const bf16x8*)&vs[d * 16 + lm][kk * 32 + lk];
                oacc[0][d] = __builtin_amdgcn_mfma_f32_16x16x32_bf16(pf[0][kk], vf, oacc[0][d], 0, 0, 0);
                oacc[1][d] = __builtin_amdgcn_mfma_f32_16x16x32_bf16(pf[1][kk], vf, oacc[1][d], 0, 0, 0);
            }
        __builtin_amdgcn_s_setprio(0);
    }
    #undef ISSUE_LOADS

    // lane-major fp16 unnormalized partials (NT 8B vector stores, coalesced)
    size_t pbase = (((size_t)n * NQB2 + qblk) * NSPLIT + sp) * (128 * 64);
    #pragma unroll
    for (int t = 0; t < 2; ++t)
        #pragma unroll
        for (int d = 0; d < 4; ++d) {
            f16x4 hv;
            #pragma unroll
            for (int r = 0; r < 4; ++r) hv[r] = (_Float16)oacc[t][d][r];
            __builtin_nontemporal_store(hv,
                (f16x4*)&o_part[pbase + (size_t)(((w * 2 + t) * 4 + d) * 256) + l * 4]);
        }
    size_t lb = (((size_t)n * NQB2 + qblk) * NSPLIT + sp) * 128;
    #pragma unroll
    for (int t = 0; t < 2; ++t) {
        float s = lsum[t];
        s += __shfl_xor(s, 16);
        s += __shfl_xor(s, 32);
        if (l < 16) lsum_g[lb + w * 32 + t * 16 + l] = s;
    }
}

// --------------------------- split-K combine (3 fp16 partials) -------------
__global__ __launch_bounds__(256) void combine_kernel(
    const _Float16* __restrict__ o_part, const float* __restrict__ lsum_g,
    short* __restrict__ o)
{
    __shared__ short ost[128][72];
    const int qblk = blockIdx.x, h = blockIdx.y;
    const int tid = threadIdx.x;
    const int w = tid >> 6, l = tid & 63;
    const int lm = l & 15, g = l >> 4;
    size_t sb = ((size_t)h * NQB2 + qblk) * NSPLIT;

    float inv[2][4];
    #pragma unroll
    for (int t = 0; t < 2; ++t)
        #pragma unroll
        for (int r = 0; r < 4; ++r) {
            int row = w * 32 + t * 16 + g * 4 + r;
            float ls = 0.f;
            #pragma unroll
            for (int s = 0; s < NSPLIT; ++s)
                ls += lsum_g[(sb + s) * 128 + row];
            inv[t][r] = 1.0f / ls;
        }
    #pragma unroll
    for (int t = 0; t < 2; ++t)
        #pragma unroll
        for (int d = 0; d < 4; ++d) {
            size_t off = (size_t)(((w * 2 + t) * 4 + d) * 256) + l * 4;
            float acc[4] = {0.f, 0.f, 0.f, 0.f};
            #pragma unroll
            for (int s = 0; s < NSPLIT; ++s) {
                f16x4 hv = nt_load_h4(&o_part[(sb + s) * 8192 + off]);
                #pragma unroll
                for (int r = 0; r < 4; ++r) acc[r] += (float)hv[r];
            }
            #pragma unroll
            for (int r = 0; r < 4; ++r)
                ost[w * 32 + t * 16 + g * 4 + r][d * 16 + lm] = f2b(acc[r] * inv[t][r]);
        }
    __syncthreads();
    const int row = tid >> 1, cb = (tid & 1) * 32;
    size_t ob = ((size_t)(qblk * 128 + row)) * DIMC + h * 64 + cb;
    #pragma unroll
    for (int v = 0; v < 4; ++v)
        *(bf16x8*)&o[ob + v * 8] = *(const bf16x8*)&ost[row][cb + v * 8];
}

// ---------------------------------------------------------------------------
extern "C" void kernel_launch(void* const* d_in, const int* in_sizes, int n_in,
                              void* d_out, int out_size, void* d_ws, size_t ws_size,
                              hipStream_t stream) {
    (void)in_sizes; (void)n_in; (void)out_size; (void)ws_size;
    const float* x         = (const float*)d_in[0];
    const float* w_qkv     = (const float*)d_in[1];
    const float* b_qkv     = (const float*)d_in[2];
    const float* w_proj    = (const float*)d_in[3];
    const float* b_proj    = (const float*)d_in[4];
    const float* rel_pos_h = (const float*)d_in[5];
    const float* rel_pos_w = (const float*)d_in[6];
    float* out = (float*)d_out;

    // region0: qkv_h (fp16) + xb + wqkvT (dead after split_rope) aliased by
    // o_part (fp16, 10.6 MB <= 17.6 MB region).
    _Float16* qkv_h  = (_Float16*)d_ws;                           // L*QKVN halfs
    short* xb        = (short*)(qkv_h + (size_t)LTOK * QKVN);     // 1,769,472 bf16
    short* wqkvT     = xb + (size_t)LTOK * DIMC;                  // 1,769,472 bf16
    float* cost      = (float*)(wqkvT + (size_t)QKVN * DIMC);     // 73,728 f32
    float* sint      = cost + (size_t)LTOK * 32;                  // 73,728 f32
    _Float16* o_part = (_Float16*)d_ws;                           // alias
    // region1: live through the whole pipeline
    short* wprojT  = (short*)(sint + (size_t)LTOK * 32);          // 589,824 bf16
    short* q_ext   = wprojT + (size_t)DIMC * DIMC;                // NH*L*128
    short* kb      = q_ext + (size_t)NH * LTOK * EXT2;            // NH*L*64
    short* vTb     = kb + (size_t)NH * LTOK * HD;                 // NH*L*64
    short* ob      = vTb + (size_t)NH * LTOK * HD;                // L*768
    short* relh_g  = ob + (size_t)LTOK * DIMC;                    // NH*L*48
    float* lsum_g  = (float*)(relh_g + (size_t)NH * LTOK * WG);   // 12*18*3*128 f32

    prep_kernel<<<dim3(NB_ROPE + NB_CAST + NB_TQKV + NB_TPRJ), 256, 0, stream>>>(
        x, w_qkv, w_proj, cost, sint, xb, wqkvT, wprojT);

    gemm_bf16_64x128_kernel<<<dim3(QKVN / 128, LTOK / 64), 256, 0, stream>>>(
        xb, wqkvT, b_qkv, qkv_h, LTOK, QKVN, DIMC);

    split_rope_relbias_kernel<<<dim3(LTOK / 64, NH), 256, 0, stream>>>(
        qkv_h, cost, sint, rel_pos_h, rel_pos_w, q_ext, kb, vTb, relh_g);

    attn_kernel<<<dim3(NQB2, NH, NSPLIT), 256, 0, stream>>>(
        q_ext, kb, vTb, relh_g, o_part, lsum_g);

    combine_kernel<<<dim3(NQB2, NH), 256, 0, stream>>>(o_part, lsum_g, ob);

    gemm32x64_kernel<<<dim3(DIMC / 64, LTOK / 32), 256, 0, stream>>>(
        ob, wprojT, b_proj, out, LTOK, DIMC, DIMC);
}